// Round 4
// baseline (206.215 us; speedup 1.0000x reference)
//
#include <hip/hip_runtime.h>

// GCN forward on MI355X:
//   out = log_softmax(adj @ (relu(adj @ (x@W1) + b1) @ W2) + b2)
// N=8192, NFEAT=512, NHID=128, NCLASS=40.
// Pipeline:
//   k0   W1 -> W1f (bf16 B-fragment-linear)
//   kcvt adj f32 -> adjf bf16 A-FRAGMENT-LINEAR (128MB; L3-resident for reuse)
//   k1   support = x@W1 -> Stf (B-fragment-linear)         [LDS-path GEMM]
//   k2   h = relu(adj@support+b1): barrier-free frag stream
//   k3   s2 = h@W2 -> S2f (B-fragment-linear, 64 cols padded)
//   k4   out = log_softmax(adj@s2+b2): barrier-free frag stream
// Fragment conventions (validated rounds 1-3):
//   A-frag (mt,kb): lane l, j -> A[mt*16+(l&15)][kb*32+(l>>4)*8+j]
//   B-frag (ct,kb): lane l, j -> B[kb*32+(l>>4)*8+j][ct*16+(l&15)]
//   C: col = ct*16+(lane&15), row = mt*16+(lane>>4)*4+i

using bf16x8 = __attribute__((ext_vector_type(8))) __bf16;
using f32x4  = __attribute__((ext_vector_type(4))) float;
using u16x4  = __attribute__((ext_vector_type(4))) unsigned short;
using u16x8  = __attribute__((ext_vector_type(8))) unsigned short;

#define NROW 8192
#define KFEAT 512
#define HID 128
#define NCLS 40

__device__ __forceinline__ unsigned short f2b(float f) {
  union { float f; unsigned u; } v; v.f = f;
  unsigned r = v.u + 0x7fffu + ((v.u >> 16) & 1u);
  return (unsigned short)(r >> 16);
}

__device__ __forceinline__ bf16x8 ldb8(const unsigned short* p) {
  return *reinterpret_cast<const bf16x8*>(p);
}

#define KBARRIER()                                        \
  asm volatile("s_waitcnt lgkmcnt(0)" ::: "memory");      \
  __builtin_amdgcn_s_barrier();                           \
  asm volatile("" ::: "memory");                          \
  __builtin_amdgcn_sched_barrier(0)

// ---- LDS-path GEMM core (used only by small k1) ----
#define GITER(T, AOUT, APRE, BCUR)                                             \
  {                                                                            \
    if ((T) + 2 < NT) {                                                        \
      APRE = *reinterpret_cast<const f32x4*>(ap + ((size_t)((T) + 2)) * 64);   \
    }                                                                          \
    const unsigned short* lb = As + (((T) & 1) << 10);                         \
    _Pragma("unroll")                                                          \
    for (int s = 0; s < 2; ++s) {                                              \
      bf16x8 af = *reinterpret_cast<const bf16x8*>(lb + (s ? aoff1 : aoff0));  \
      _Pragma("unroll")                                                        \
      for (int c = 0; c < NC; ++c)                                             \
        acc[c] = __builtin_amdgcn_mfma_f32_16x16x32_bf16(af, BCUR[c][s],       \
                                                         acc[c], 0, 0, 0);    \
    }                                                                          \
    if ((T) + 2 < NT) {                                                        \
      _Pragma("unroll")                                                        \
      for (int c = 0; c < NC; ++c) {                                           \
        BCUR[c][0] = ldb8(bp[c] + ((size_t)((T) + 2)) * 1024);                 \
        BCUR[c][1] = ldb8(bp[c] + ((size_t)((T) + 2)) * 1024 + 512);           \
      }                                                                        \
    }                                                                          \
    if ((T) + 1 < NT) {                                                        \
      u16x4 pk;                                                                \
      pk[0] = f2b(AOUT[0]); pk[1] = f2b(AOUT[1]);                              \
      pk[2] = f2b(AOUT[2]); pk[3] = f2b(AOUT[3]);                              \
      *reinterpret_cast<u16x4*>(As + ((((T) + 1) & 1) << 10) + swoff) = pk;    \
    }                                                                          \
    KBARRIER();                                                                \
  }

template<int NT, int NC, int LDA_>
__device__ __forceinline__ void gemm16f(const float* __restrict__ Ab,
                                        const unsigned short* __restrict__ Bf,
                                        unsigned short* As,      // [2*1024]
                                        f32x4 (&acc)[NC], int tid)
{
  const int lane = tid & 63;
  const int wave = tid >> 6;
  const int l15 = lane & 15, lg = lane >> 4;
  const int srow = tid >> 4;
  const int sc4  = (tid & 15) * 4;
  const float* ap = Ab + (size_t)srow * LDA_ + sc4;
  const int swoff = (srow * 64 + sc4) ^ ((srow & 7) << 3);
  const unsigned short* bp[NC];
#pragma unroll
  for (int c = 0; c < NC; ++c)
    bp[c] = Bf + (size_t)(wave * NC + c) * (NT * 2) * 512 + lane * 8;
  const int aoff0 = (l15 * 64 + lg * 8) ^ ((l15 & 7) << 3);
  const int aoff1 = (l15 * 64 + 32 + lg * 8) ^ ((l15 & 7) << 3);

  f32x4 aX, aY;
  bf16x8 bA[NC][2], bB[NC][2];
  {
    f32x4 a0 = *reinterpret_cast<const f32x4*>(ap);
    aX = *reinterpret_cast<const f32x4*>(ap + 64);
#pragma unroll
    for (int c = 0; c < NC; ++c) {
      bA[c][0] = ldb8(bp[c]);        bA[c][1] = ldb8(bp[c] + 512);
      bB[c][0] = ldb8(bp[c] + 1024); bB[c][1] = ldb8(bp[c] + 1536);
    }
    u16x4 pk;
    pk[0] = f2b(a0[0]); pk[1] = f2b(a0[1]); pk[2] = f2b(a0[2]); pk[3] = f2b(a0[3]);
    *reinterpret_cast<u16x4*>(As + swoff) = pk;
    KBARRIER();
  }
  for (int t = 0; t < NT; t += 2) {
    GITER(t,     aX, aY, bA);
    GITER(t + 1, aY, aX, bB);
  }
}

// K0: W1f B-fragment-linear from W1[512][128]
__global__ __launch_bounds__(256) void k0_w1f(const float* __restrict__ W1,
                                              unsigned short* __restrict__ W1f)
{
  int id = blockIdx.x * 256 + threadIdx.x;   // 0..8191
  int l16 = id & 63, blkid = id >> 6;
  int kb = blkid & 15, ct = blkid >> 4;
  int c = ct * 16 + (l16 & 15);
  int k0 = kb * 32 + (l16 >> 4) * 8;
  u16x8 pk;
#pragma unroll
  for (int j = 0; j < 8; ++j) pk[j] = f2b(W1[(size_t)(k0 + j) * HID + c]);
  *reinterpret_cast<u16x8*>(W1f + (size_t)id * 8) = pk;
}

// KCVT: adj f32 [8192][8192] -> adjf bf16 A-fragment-linear.
// Block: 16 rows x 512 cols tile via LDS transpose. Reads 256B-contiguous
// per wave-instr; writes 1KB-contiguous per kb.
__global__ __launch_bounds__(256) void k_adjcvt(const float* __restrict__ ADJ,
                                                unsigned short* __restrict__ AF)
{
  __shared__ unsigned short Ls[16 * 528];   // row pad 528 u16
  const int t = threadIdx.x;
  const int mt = blockIdx.x >> 4;           // 0..511
  const int kg = blockIdx.x & 15;           // 0..15
  {
    const int r  = t >> 4;                  // 0..15
    const int c4 = (t & 15) * 4;            // 0..60
    const float* src = ADJ + (size_t)(mt * 16 + r) * NROW + kg * 512 + c4;
    unsigned short* lp = &Ls[r * 528 + c4];
#pragma unroll
    for (int i = 0; i < 8; ++i) {
      f32x4 f = *reinterpret_cast<const f32x4*>(src + i * 64);
      u16x4 pk;
      pk[0] = f2b(f[0]); pk[1] = f2b(f[1]); pk[2] = f2b(f[2]); pk[3] = f2b(f[3]);
      *reinterpret_cast<u16x4*>(lp + i * 64) = pk;
    }
  }
  __syncthreads();
  {
    const int kb = t >> 4;                  // 0..15 (local)
    const int p  = t & 15;
    unsigned short* dst = AF + ((size_t)mt * 256 + kg * 16 + kb) * 512 + p * 32;
#pragma unroll
    for (int i = 0; i < 4; ++i) {
      const int l = p * 4 + i;              // lane 0..63
      const unsigned short* s = &Ls[(l & 15) * 528 + kb * 32 + (l >> 4) * 8];
      *reinterpret_cast<u16x8*>(dst + i * 8) = *reinterpret_cast<const u16x8*>(s);
    }
  }
}

// K1: support = x @ W1 -> Stf B-fragment-linear (KB=256 over m)
__global__ __launch_bounds__(256) void k1_support(const float* __restrict__ X,
                                                  const unsigned short* __restrict__ W1f,
                                                  unsigned short* __restrict__ Stf)
{
  __shared__ unsigned short As[2 * 1024];
  const int tid = threadIdx.x;
  const int blk = blockIdx.x;
  const int m0 = blk * 16;
  f32x4 acc[2] = {};
  constexpr int NT = KFEAT / 64, NC = 2;
  gemm16f<NT, NC, KFEAT>(X + (size_t)m0 * KFEAT, W1f, As, acc, tid);
  const int lane = tid & 63, wave = tid >> 6;
  const int l15 = lane & 15, lg = lane >> 4;
  const int kb  = blk >> 1;
  const int lgc = ((blk & 1) << 1) + (lg >> 1);
  const int jb  = (lg & 1) * 4;
#pragma unroll
  for (int c = 0; c < 2; ++c) {
    int ctc = wave * 2 + c;
    u16x4 pk;
#pragma unroll
    for (int i = 0; i < 4; ++i) pk[i] = f2b(acc[c][i]);
    *reinterpret_cast<u16x4*>(Stf + (size_t)(ctc * 256 + kb) * 512 +
                              (l15 + 16 * lgc) * 8 + jb) = pk;
  }
}

// K2: h = relu(adj@support + b1). Barrier-free fragment stream, depth-4 pipe.
// 4 waves/block share the A stream (L1/L2 dedup), wave w owns cols 32w..32w+31.
__global__ __launch_bounds__(256) void k2_hidden(const unsigned short* __restrict__ AF,
                                                 const unsigned short* __restrict__ Stf,
                                                 const float* __restrict__ b1,
                                                 unsigned short* __restrict__ H)
{
  const int tid = threadIdx.x;
  const int lane = tid & 63, wave = tid >> 6;
  const int l15 = lane & 15, lg = lane >> 4;
  const int mt = blockIdx.x;
  const unsigned short* ap  = AF  + (size_t)mt * 131072 + lane * 8;
  const unsigned short* bp0 = Stf + (size_t)(wave * 2    ) * 131072 + lane * 8;
  const unsigned short* bp1 = Stf + (size_t)(wave * 2 + 1) * 131072 + lane * 8;

  f32x4 acc0 = {}, acc1 = {};
  bf16x8 Ar[4], B0r[4], B1r[4];
#pragma unroll
  for (int ph = 0; ph < 4; ++ph) {
    Ar[ph]  = ldb8(ap  + ph * 512);
    B0r[ph] = ldb8(bp0 + ph * 512);
    B1r[ph] = ldb8(bp1 + ph * 512);
  }
#pragma unroll 1
  for (int kb = 0; kb < 252; kb += 4) {
#pragma unroll
    for (int ph = 0; ph < 4; ++ph) {
      acc0 = __builtin_amdgcn_mfma_f32_16x16x32_bf16(Ar[ph], B0r[ph], acc0, 0, 0, 0);
      acc1 = __builtin_amdgcn_mfma_f32_16x16x32_bf16(Ar[ph], B1r[ph], acc1, 0, 0, 0);
      Ar[ph]  = ldb8(ap  + (kb + 4 + ph) * 512);
      B0r[ph] = ldb8(bp0 + (kb + 4 + ph) * 512);
      B1r[ph] = ldb8(bp1 + (kb + 4 + ph) * 512);
    }
  }
#pragma unroll
  for (int ph = 0; ph < 4; ++ph) {
    acc0 = __builtin_amdgcn_mfma_f32_16x16x32_bf16(Ar[ph], B0r[ph], acc0, 0, 0, 0);
    acc1 = __builtin_amdgcn_mfma_f32_16x16x32_bf16(Ar[ph], B1r[ph], acc1, 0, 0, 0);
  }
  {
    f32x4 a[2] = {acc0, acc1};
#pragma unroll
    for (int c = 0; c < 2; ++c) {
      int col = (wave * 2 + c) * 16 + l15;
      float bias = b1[col];
#pragma unroll
      for (int i = 0; i < 4; ++i) {
        int mm = mt * 16 + lg * 4 + i;
        float v = a[c][i] + bias;
        v = v > 0.f ? v : 0.f;
        H[(size_t)mm * HID + col] = f2b(v);
      }
    }
  }
}

// K3: s2 = h @ W2 -> S2f B-fragment-linear (64 cols, 40..63 zero pad)
__global__ __launch_bounds__(256) void k3_s2(const unsigned short* __restrict__ H,
                                             const float* __restrict__ W2,
                                             unsigned short* __restrict__ S2f)
{
  __shared__ unsigned short W2t[64 * 136];
  const int tid = threadIdx.x;
  {
    const int n = tid >> 2;
    const int ks = (tid & 3) * 32;
    for (int j = 0; j < 32; ++j) {
      int k = ks + j;
      float v = (n < NCLS) ? W2[k * NCLS + n] : 0.f;
      W2t[n * 136 + k] = f2b(v);
    }
  }
  __syncthreads();
  const int lane = tid & 63, wave = tid >> 6;
  const int l15 = lane & 15, lg = lane >> 4;
  const int blk = blockIdx.x;
  const int m0 = blk * 64;
  const int rowm = m0 + wave * 16 + l15;
  f32x4 acc[4] = {};
#pragma unroll
  for (int kk = 0; kk < 4; ++kk) {
    bf16x8 af = *reinterpret_cast<const bf16x8*>(H + (size_t)rowm * HID + kk * 32 + lg * 8);
#pragma unroll
    for (int n = 0; n < 4; ++n) {
      bf16x8 bf = *reinterpret_cast<const bf16x8*>(&W2t[(n * 16 + l15) * 136 + kk * 32 + lg * 8]);
      acc[n] = __builtin_amdgcn_mfma_f32_16x16x32_bf16(af, bf, acc[n], 0, 0, 0);
    }
  }
  const int kb  = blk * 2 + (wave >> 1);
  const int lgc = ((wave & 1) << 1) + (lg >> 1);
  const int jb  = (lg & 1) * 4;
#pragma unroll
  for (int n = 0; n < 4; ++n) {
    u16x4 pk;
#pragma unroll
    for (int i = 0; i < 4; ++i) pk[i] = f2b(acc[n][i]);
    *reinterpret_cast<u16x4*>(S2f + (size_t)(n * 256 + kb) * 512 +
                              (l15 + 16 * lgc) * 8 + jb) = pk;
  }
}

// K4: out = log_softmax(adj@s2 + b2). Barrier-free fragment stream, depth-4.
__global__ __launch_bounds__(256) void k4_out(const unsigned short* __restrict__ AF,
                                              const unsigned short* __restrict__ S2f,
                                              const float* __restrict__ b2,
                                              float* __restrict__ OUT)
{
  __shared__ float Ll[16 * 65];
  const int tid = threadIdx.x;
  const int lane = tid & 63, wave = tid >> 6;
  const int l15 = lane & 15, lg = lane >> 4;
  const int mt = blockIdx.x;
  const unsigned short* ap = AF  + (size_t)mt * 131072 + lane * 8;
  const unsigned short* bp = S2f + (size_t)wave * 131072 + lane * 8;

  f32x4 acc = {};
  bf16x8 Ar[4], Br[4];
#pragma unroll
  for (int ph = 0; ph < 4; ++ph) {
    Ar[ph] = ldb8(ap + ph * 512);
    Br[ph] = ldb8(bp + ph * 512);
  }
#pragma unroll 1
  for (int kb = 0; kb < 252; kb += 4) {
#pragma unroll
    for (int ph = 0; ph < 4; ++ph) {
      acc = __builtin_amdgcn_mfma_f32_16x16x32_bf16(Ar[ph], Br[ph], acc, 0, 0, 0);
      Ar[ph] = ldb8(ap + (kb + 4 + ph) * 512);
      Br[ph] = ldb8(bp + (kb + 4 + ph) * 512);
    }
  }
#pragma unroll
  for (int ph = 0; ph < 4; ++ph)
    acc = __builtin_amdgcn_mfma_f32_16x16x32_bf16(Ar[ph], Br[ph], acc, 0, 0, 0);

  const int col = wave * 16 + l15;
  if (col < NCLS) {
    const float bias = b2[col];
#pragma unroll
    for (int i = 0; i < 4; ++i) {
      int row = lg * 4 + i;
      Ll[row * 65 + col] = acc[i] + bias;
    }
  }
  __syncthreads();
  const int row = tid >> 4;   // 0..15
  const int sub = tid & 15;
  float vals[3];
  int nc = 0;
  float mx = -3.4e38f;
  for (int c = sub; c < NCLS; c += 16) {
    float v = Ll[row * 65 + c];
    vals[nc++] = v;
    mx = fmaxf(mx, v);
  }
#pragma unroll
  for (int d = 1; d < 16; d <<= 1) mx = fmaxf(mx, __shfl_xor(mx, d));
  float se = 0.f;
  for (int j = 0; j < nc; ++j) se += expf(vals[j] - mx);
#pragma unroll
  for (int d = 1; d < 16; d <<= 1) se += __shfl_xor(se, d);
  const float lse = mx + logf(se);
  int j = 0;
  for (int c = sub; c < NCLS; c += 16) {
    OUT[(size_t)(mt * 16 + row) * NCLS + c] = vals[j++] - lse;
  }
}

extern "C" void kernel_launch(void* const* d_in, const int* in_sizes, int n_in,
                              void* d_out, int out_size, void* d_ws, size_t ws_size,
                              hipStream_t stream)
{
  const float* x   = (const float*)d_in[0];
  const float* adj = (const float*)d_in[1];
  const float* W1  = (const float*)d_in[2];
  const float* b1  = (const float*)d_in[3];
  const float* W2  = (const float*)d_in[4];
  const float* b2  = (const float*)d_in[5];
  float* out = (float*)d_out;

  char* ws = (char*)d_ws;
  unsigned short* W1f = (unsigned short*)(ws);                          // 128KB
  unsigned short* Stf = (unsigned short*)(ws + 131072);                 // 2MB
  unsigned short* H   = (unsigned short*)(ws + 131072 + 2097152);       // 2MB
  unsigned short* S2f = (unsigned short*)(ws + 131072 + 2 * 2097152);   // 1MB
  unsigned short* AF  = (unsigned short*)(ws + (size_t)16777216);       // 134MB

  hipLaunchKernelGGL(k0_w1f,     dim3(32),   dim3(256), 0, stream, W1, W1f);
  hipLaunchKernelGGL(k_adjcvt,   dim3(8192), dim3(256), 0, stream, adj, AF);
  hipLaunchKernelGGL(k1_support, dim3(512),  dim3(256), 0, stream, x, W1f, Stf);
  hipLaunchKernelGGL(k2_hidden,  dim3(512),  dim3(256), 0, stream, AF, Stf, b1, H);
  hipLaunchKernelGGL(k3_s2,      dim3(128),  dim3(256), 0, stream, H, W2, S2f);
  hipLaunchKernelGGL(k4_out,     dim3(512),  dim3(256), 0, stream, AF, S2f, b2, out);
}

// Round 5
// 142.827 us; speedup vs baseline: 1.4438x; 1.4438x over previous
//
#include <hip/hip_runtime.h>

// GCN forward on MI355X:
//   out = log_softmax(adj @ (relu(adj @ (x@W1) + b1) @ W2) + b2)
// N=8192, NFEAT=512, NHID=128, NCLASS=40. adj is 256MB f32, SYMMETRIC.
// Key trick: compute h^T = S^T @ adj (adj as B operand). By symmetry the
// B-fragment read of adj is 2 contiguous f32x4 per lane along adj rows ->
// barrier-free, LDS-free streaming in the two big kernels. A operands are the
// small fragment-linear bf16 intermediates (L2-resident, contiguous 1KB/wave).
//   k0   W1 -> W1f  (bf16 B-fragment-linear)
//   k1   support = x@W1 -> Stf (B-fragment-linear)     [LDS-path GEMM, small]
//   k2   h^T = S^T@adj (+bias,relu) -> H row-major bf16 [8192][128]
//   k3   s2 = h@W2 -> S2f (B-fragment-linear, 64 cols, 40..63 zero)
//   k4   logits^T = s2^T@adj (+bias) -> log_softmax -> OUT f32 [8192][40]
// Fragment conventions (validated rounds 1-4):
//   A-frag (mt,kb): lane l, j -> A[mt*16+(l&15)][kb*32+(l>>4)*8+j]
//   B-frag (ct,kb): lane l, j -> B[kb*32+(l>>4)*8+j][ct*16+(l&15)]
//   C/D: N-side col = ct*16+(lane&15), M-side row = mt*16+(lane>>4)*4+i

using bf16x8 = __attribute__((ext_vector_type(8))) __bf16;
using f32x4  = __attribute__((ext_vector_type(4))) float;
using u16x4  = __attribute__((ext_vector_type(4))) unsigned short;
using u16x8  = __attribute__((ext_vector_type(8))) unsigned short;

#define NROW 8192
#define KFEAT 512
#define HID 128
#define NCLS 40

__device__ __forceinline__ unsigned short f2b(float f) {
  union { float f; unsigned u; } v; v.f = f;
  unsigned r = v.u + 0x7fffu + ((v.u >> 16) & 1u);
  return (unsigned short)(r >> 16);
}

__device__ __forceinline__ bf16x8 ldb8(const unsigned short* p) {
  return *reinterpret_cast<const bf16x8*>(p);
}

#define KBARRIER()                                        \
  asm volatile("s_waitcnt lgkmcnt(0)" ::: "memory");      \
  __builtin_amdgcn_s_barrier();                           \
  asm volatile("" ::: "memory");                          \
  __builtin_amdgcn_sched_barrier(0)

// ---- LDS-path GEMM core (only k1 uses it; small) ----
#define GITER(T, AOUT, APRE, BCUR)                                             \
  {                                                                            \
    if ((T) + 2 < NT) {                                                        \
      APRE = *reinterpret_cast<const f32x4*>(ap + ((size_t)((T) + 2)) * 64);   \
    }                                                                          \
    const unsigned short* lb = As + (((T) & 1) << 10);                         \
    _Pragma("unroll")                                                          \
    for (int s = 0; s < 2; ++s) {                                              \
      bf16x8 af = *reinterpret_cast<const bf16x8*>(lb + (s ? aoff1 : aoff0));  \
      _Pragma("unroll")                                                        \
      for (int c = 0; c < NC; ++c)                                             \
        acc[c] = __builtin_amdgcn_mfma_f32_16x16x32_bf16(af, BCUR[c][s],       \
                                                         acc[c], 0, 0, 0);    \
    }                                                                          \
    if ((T) + 2 < NT) {                                                        \
      _Pragma("unroll")                                                        \
      for (int c = 0; c < NC; ++c) {                                           \
        BCUR[c][0] = ldb8(bp[c] + ((size_t)((T) + 2)) * 1024);                 \
        BCUR[c][1] = ldb8(bp[c] + ((size_t)((T) + 2)) * 1024 + 512);           \
      }                                                                        \
    }                                                                          \
    if ((T) + 1 < NT) {                                                        \
      u16x4 pk;                                                                \
      pk[0] = f2b(AOUT[0]); pk[1] = f2b(AOUT[1]);                              \
      pk[2] = f2b(AOUT[2]); pk[3] = f2b(AOUT[3]);                              \
      *reinterpret_cast<u16x4*>(As + ((((T) + 1) & 1) << 10) + swoff) = pk;    \
    }                                                                          \
    KBARRIER();                                                                \
  }

template<int NT, int NC, int LDA_>
__device__ __forceinline__ void gemm16f(const float* __restrict__ Ab,
                                        const unsigned short* __restrict__ Bf,
                                        unsigned short* As,      // [2*1024]
                                        f32x4 (&acc)[NC], int tid)
{
  const int lane = tid & 63;
  const int wave = tid >> 6;
  const int l15 = lane & 15, lg = lane >> 4;
  const int srow = tid >> 4;
  const int sc4  = (tid & 15) * 4;
  const float* ap = Ab + (size_t)srow * LDA_ + sc4;
  const int swoff = (srow * 64 + sc4) ^ ((srow & 7) << 3);
  const unsigned short* bp[NC];
#pragma unroll
  for (int c = 0; c < NC; ++c)
    bp[c] = Bf + (size_t)(wave * NC + c) * (NT * 2) * 512 + lane * 8;
  const int aoff0 = (l15 * 64 + lg * 8) ^ ((l15 & 7) << 3);
  const int aoff1 = (l15 * 64 + 32 + lg * 8) ^ ((l15 & 7) << 3);

  f32x4 aX, aY;
  bf16x8 bA[NC][2], bB[NC][2];
  {
    f32x4 a0 = *reinterpret_cast<const f32x4*>(ap);
    aX = *reinterpret_cast<const f32x4*>(ap + 64);
#pragma unroll
    for (int c = 0; c < NC; ++c) {
      bA[c][0] = ldb8(bp[c]);        bA[c][1] = ldb8(bp[c] + 512);
      bB[c][0] = ldb8(bp[c] + 1024); bB[c][1] = ldb8(bp[c] + 1536);
    }
    u16x4 pk;
    pk[0] = f2b(a0[0]); pk[1] = f2b(a0[1]); pk[2] = f2b(a0[2]); pk[3] = f2b(a0[3]);
    *reinterpret_cast<u16x4*>(As + swoff) = pk;
    KBARRIER();
  }
  for (int t = 0; t < NT; t += 2) {
    GITER(t,     aX, aY, bA);
    GITER(t + 1, aY, aX, bB);
  }
}

// K0: W1f B-fragment-linear from W1[512][128]
__global__ __launch_bounds__(256) void k0_w1f(const float* __restrict__ W1,
                                              unsigned short* __restrict__ W1f)
{
  int id = blockIdx.x * 256 + threadIdx.x;   // 0..8191
  int l16 = id & 63, blkid = id >> 6;
  int kb = blkid & 15, ct = blkid >> 4;
  int c = ct * 16 + (l16 & 15);
  int k0 = kb * 32 + (l16 >> 4) * 8;
  u16x8 pk;
#pragma unroll
  for (int j = 0; j < 8; ++j) pk[j] = f2b(W1[(size_t)(k0 + j) * HID + c]);
  *reinterpret_cast<u16x8*>(W1f + (size_t)id * 8) = pk;
}

// K1: support = x @ W1 -> Stf B-fragment-linear (kb over m, 256 kbs)
__global__ __launch_bounds__(256) void k1_support(const float* __restrict__ X,
                                                  const unsigned short* __restrict__ W1f,
                                                  unsigned short* __restrict__ Stf)
{
  __shared__ unsigned short As[2 * 1024];
  const int tid = threadIdx.x;
  const int blk = blockIdx.x;
  const int m0 = blk * 16;
  f32x4 acc[2] = {};
  constexpr int NT = KFEAT / 64, NC = 2;
  gemm16f<NT, NC, KFEAT>(X + (size_t)m0 * KFEAT, W1f, As, acc, tid);
  const int lane = tid & 63, wave = tid >> 6;
  const int l15 = lane & 15, lg = lane >> 4;
  const int kb  = blk >> 1;
  const int lgc = ((blk & 1) << 1) + (lg >> 1);
  const int jb  = (lg & 1) * 4;
#pragma unroll
  for (int c = 0; c < 2; ++c) {
    int ctc = wave * 2 + c;
    u16x4 pk;
#pragma unroll
    for (int i = 0; i < 4; ++i) pk[i] = f2b(acc[c][i]);
    *reinterpret_cast<u16x4*>(Stf + (size_t)(ctc * 256 + kb) * 512 +
                              (l15 + 16 * lgc) * 8 + jb) = pk;
  }
}

// ---- Barrier-free adj-stream body (adj as B via symmetry) ----
// MT A-frag tiles, 2 adj-row tiles (32 rows/block), X/Y depth-1 pipeline.
#define KBADJ(IT, NIT, MT, AC, AN, BC, BN)                                     \
  {                                                                            \
    if ((IT) + 1 < (NIT)) {                                                    \
      _Pragma("unroll")                                                        \
      for (int mt = 0; mt < (MT); ++mt)                                        \
        AN[mt] = ldb8(apt + ((size_t)(mt * 256 + kbg0 + (IT) + 1) << 9));      \
      BN[0] = *reinterpret_cast<const f32x4*>(bpt0 + ((IT) + 1) * 32);         \
      BN[1] = *reinterpret_cast<const f32x4*>(bpt0 + ((IT) + 1) * 32 + 4);     \
      BN[2] = *reinterpret_cast<const f32x4*>(bpt1 + ((IT) + 1) * 32);         \
      BN[3] = *reinterpret_cast<const f32x4*>(bpt1 + ((IT) + 1) * 32 + 4);     \
    }                                                                          \
    u16x8 t0, t1;                                                              \
    _Pragma("unroll")                                                          \
    for (int j = 0; j < 4; ++j) {                                              \
      t0[j]     = f2b(BC[0][j]);  t0[j + 4] = f2b(BC[1][j]);                   \
      t1[j]     = f2b(BC[2][j]);  t1[j + 4] = f2b(BC[3][j]);                   \
    }                                                                          \
    bf16x8 f0 = __builtin_bit_cast(bf16x8, t0);                                \
    bf16x8 f1 = __builtin_bit_cast(bf16x8, t1);                                \
    _Pragma("unroll")                                                          \
    for (int mt = 0; mt < (MT); ++mt) {                                        \
      acc[mt][0] = __builtin_amdgcn_mfma_f32_16x16x32_bf16(AC[mt], f0,         \
                                                           acc[mt][0], 0,0,0); \
      acc[mt][1] = __builtin_amdgcn_mfma_f32_16x16x32_bf16(AC[mt], f1,         \
                                                           acc[mt][1], 0,0,0); \
    }                                                                          \
  }

// K2: h^T = S^T @ adj. Block = 32 adj rows, 512 threads, 8-wave K-split
// (each wave K=1024 = 32 kb-steps, no sync in hot loop). LDS reduce at end.
__global__ __launch_bounds__(512, 2) void k2_hidden(const float* __restrict__ ADJ,
                                                    const unsigned short* __restrict__ Stf,
                                                    const float* __restrict__ b1,
                                                    unsigned short* __restrict__ H)
{
  __shared__ float Ls[8 * 4096];            // 128 KB: per-wave partial C
  __shared__ unsigned short Hs[32 * 128];   // 8 KB staging for coalesced store
  const int tid = threadIdx.x;
  const int lane = tid & 63, w = tid >> 6;
  const int l15 = lane & 15, lg = lane >> 4;
  const int n0 = blockIdx.x * 32;
  const int kbg0 = w * 32;

  const float* bpt0 = ADJ + (size_t)(n0 + l15) * NROW + kbg0 * 32 + lg * 8;
  const float* bpt1 = bpt0 + (size_t)16 * NROW;
  const unsigned short* apt = Stf + lane * 8;

  f32x4 acc[8][2];
#pragma unroll
  for (int m = 0; m < 8; ++m) { acc[m][0] = f32x4{}; acc[m][1] = f32x4{}; }

  bf16x8 aX[8], aY[8];
  f32x4 bX[4], bY[4];
#pragma unroll
  for (int mt = 0; mt < 8; ++mt)
    aX[mt] = ldb8(apt + ((size_t)(mt * 256 + kbg0) << 9));
  bX[0] = *reinterpret_cast<const f32x4*>(bpt0);
  bX[1] = *reinterpret_cast<const f32x4*>(bpt0 + 4);
  bX[2] = *reinterpret_cast<const f32x4*>(bpt1);
  bX[3] = *reinterpret_cast<const f32x4*>(bpt1 + 4);

  for (int it = 0; it < 32; it += 2) {
    KBADJ(it,     32, 8, aX, aY, bX, bY);
    KBADJ(it + 1, 32, 8, aY, aX, bY, bX);
  }

  // partials -> LDS: element e = c*32 + nl (c = hidden 0..127, nl = row 0..31)
#pragma unroll
  for (int mt = 0; mt < 8; ++mt)
#pragma unroll
    for (int c2 = 0; c2 < 2; ++c2)
#pragma unroll
      for (int i = 0; i < 4; ++i)
        Ls[w * 4096 + (mt * 16 + lg * 4 + i) * 32 + c2 * 16 + l15] = acc[mt][c2][i];
  __syncthreads();

  // reduce 8 slabs: thread -> 8 elems (same c, nl0..nl0+7)
  {
    const int e0 = tid * 8;
    f32x4 s0 = {}, s1 = {};
#pragma unroll
    for (int ww = 0; ww < 8; ++ww) {
      s0 += *reinterpret_cast<const f32x4*>(&Ls[ww * 4096 + e0]);
      s1 += *reinterpret_cast<const f32x4*>(&Ls[ww * 4096 + e0 + 4]);
    }
    const int c = e0 >> 5;
    const int nl0 = e0 & 31;
    const float bias = b1[c];
    float v[8];
#pragma unroll
    for (int j = 0; j < 4; ++j) { v[j] = s0[j] + bias; v[j + 4] = s1[j] + bias; }
#pragma unroll
    for (int j = 0; j < 8; ++j) {
      float r = v[j] > 0.f ? v[j] : 0.f;
      Hs[(nl0 + j) * 128 + c] = f2b(r);
    }
  }
  __syncthreads();
  // coalesced store: thread -> row nl = tid>>4, cols (tid&15)*8..+7
  {
    const int nl = tid >> 4, cc = (tid & 15) * 8;
    u16x8 vv = *reinterpret_cast<const u16x8*>(&Hs[nl * 128 + cc]);
    *reinterpret_cast<u16x8*>(H + (size_t)(n0 + nl) * HID + cc) = vv;
  }
}

// K3: s2 = h @ W2 -> S2f B-fragment-linear (64 cols, 40..63 zero pad)
__global__ __launch_bounds__(256) void k3_s2(const unsigned short* __restrict__ H,
                                             const float* __restrict__ W2,
                                             unsigned short* __restrict__ S2f)
{
  __shared__ unsigned short W2t[64 * 136];
  const int tid = threadIdx.x;
  {
    const int n = tid >> 2;
    const int ks = (tid & 3) * 32;
    for (int j = 0; j < 32; ++j) {
      int k = ks + j;
      float v = (n < NCLS) ? W2[k * NCLS + n] : 0.f;
      W2t[n * 136 + k] = f2b(v);
    }
  }
  __syncthreads();
  const int lane = tid & 63, wave = tid >> 6;
  const int l15 = lane & 15, lg = lane >> 4;
  const int blk = blockIdx.x;
  const int m0 = blk * 64;
  const int rowm = m0 + wave * 16 + l15;
  f32x4 acc[4] = {};
#pragma unroll
  for (int kk = 0; kk < 4; ++kk) {
    bf16x8 af = *reinterpret_cast<const bf16x8*>(H + (size_t)rowm * HID + kk * 32 + lg * 8);
#pragma unroll
    for (int n = 0; n < 4; ++n) {
      bf16x8 bf = *reinterpret_cast<const bf16x8*>(&W2t[(n * 16 + l15) * 136 + kk * 32 + lg * 8]);
      acc[n] = __builtin_amdgcn_mfma_f32_16x16x32_bf16(af, bf, acc[n], 0, 0, 0);
    }
  }
  const int kb  = blk * 2 + (wave >> 1);
  const int lgc = ((wave & 1) << 1) + (lg >> 1);
  const int jb  = (lg & 1) * 4;
#pragma unroll
  for (int n = 0; n < 4; ++n) {
    u16x4 pk;
#pragma unroll
    for (int i = 0; i < 4; ++i) pk[i] = f2b(acc[n][i]);
    *reinterpret_cast<u16x4*>(S2f + (size_t)(n * 256 + kb) * 512 +
                              (l15 + 16 * lgc) * 8 + jb) = pk;
  }
}

// K4: logits^T = s2^T @ adj (+b2), then per-row log_softmax. Same stream
// structure as K2 with MT=4. OUT f32 [8192][40].
__global__ __launch_bounds__(512, 2) void k4_out(const float* __restrict__ ADJ,
                                                 const unsigned short* __restrict__ S2f,
                                                 const float* __restrict__ b2,
                                                 float* __restrict__ OUT)
{
  __shared__ float Ls[8 * 2048];   // 64 KB
  __shared__ float Lg[32 * 64];    // 8 KB logits [row][class]
  const int tid = threadIdx.x;
  const int lane = tid & 63, w = tid >> 6;
  const int l15 = lane & 15, lg = lane >> 4;
  const int n0 = blockIdx.x * 32;
  const int kbg0 = w * 32;

  const float* bpt0 = ADJ + (size_t)(n0 + l15) * NROW + kbg0 * 32 + lg * 8;
  const float* bpt1 = bpt0 + (size_t)16 * NROW;
  const unsigned short* apt = S2f + lane * 8;

  f32x4 acc[4][2];
#pragma unroll
  for (int m = 0; m < 4; ++m) { acc[m][0] = f32x4{}; acc[m][1] = f32x4{}; }

  bf16x8 aX[4], aY[4];
  f32x4 bX[4], bY[4];
#pragma unroll
  for (int mt = 0; mt < 4; ++mt)
    aX[mt] = ldb8(apt + ((size_t)(mt * 256 + kbg0) << 9));
  bX[0] = *reinterpret_cast<const f32x4*>(bpt0);
  bX[1] = *reinterpret_cast<const f32x4*>(bpt0 + 4);
  bX[2] = *reinterpret_cast<const f32x4*>(bpt1);
  bX[3] = *reinterpret_cast<const f32x4*>(bpt1 + 4);

  for (int it = 0; it < 32; it += 2) {
    KBADJ(it,     32, 4, aX, aY, bX, bY);
    KBADJ(it + 1, 32, 4, aY, aX, bY, bX);
  }

#pragma unroll
  for (int mt = 0; mt < 4; ++mt)
#pragma unroll
    for (int c2 = 0; c2 < 2; ++c2)
#pragma unroll
      for (int i = 0; i < 4; ++i)
        Ls[w * 2048 + (mt * 16 + lg * 4 + i) * 32 + c2 * 16 + l15] = acc[mt][c2][i];
  __syncthreads();

  // reduce: thread -> 4 elems (same class c, rows nl0..nl0+3)
  {
    const int e0 = tid * 4;
    f32x4 s = {};
#pragma unroll
    for (int ww = 0; ww < 8; ++ww)
      s += *reinterpret_cast<const f32x4*>(&Ls[ww * 2048 + e0]);
    const int c = e0 >> 5;
    const int nl0 = e0 & 31;
    const float bias = (c < NCLS) ? b2[c] : 0.f;
#pragma unroll
    for (int j = 0; j < 4; ++j)
      Lg[(nl0 + j) * 64 + c] = s[j] + bias;
  }
  __syncthreads();

  // log_softmax: 32 rows x 16 threads
  {
    const int row = tid >> 4;
    const int sub = tid & 15;
    float vals[3];
    int nc = 0;
    float mx = -3.4e38f;
    for (int c = sub; c < NCLS; c += 16) {
      float v = Lg[row * 64 + c];
      vals[nc++] = v;
      mx = fmaxf(mx, v);
    }
#pragma unroll
    for (int d = 1; d < 16; d <<= 1) mx = fmaxf(mx, __shfl_xor(mx, d));
    float se = 0.f;
    for (int j = 0; j < nc; ++j) se += expf(vals[j] - mx);
#pragma unroll
    for (int d = 1; d < 16; d <<= 1) se += __shfl_xor(se, d);
    const float lse = mx + logf(se);
    int j = 0;
    for (int c = sub; c < NCLS; c += 16)
      OUT[(size_t)(n0 + row) * NCLS + c] = vals[j++] - lse;
  }
}

extern "C" void kernel_launch(void* const* d_in, const int* in_sizes, int n_in,
                              void* d_out, int out_size, void* d_ws, size_t ws_size,
                              hipStream_t stream)
{
  const float* x   = (const float*)d_in[0];
  const float* adj = (const float*)d_in[1];
  const float* W1  = (const float*)d_in[2];
  const float* b1  = (const float*)d_in[3];
  const float* W2  = (const float*)d_in[4];
  const float* b2  = (const float*)d_in[5];
  float* out = (float*)d_out;

  char* ws = (char*)d_ws;
  unsigned short* W1f = (unsigned short*)(ws);                          // 128KB
  unsigned short* Stf = (unsigned short*)(ws + 131072);                 // 2MB
  unsigned short* H   = (unsigned short*)(ws + 131072 + 2097152);       // 2MB
  unsigned short* S2f = (unsigned short*)(ws + 131072 + 2 * 2097152);   // 1MB

  hipLaunchKernelGGL(k0_w1f,     dim3(32),  dim3(256), 0, stream, W1, W1f);
  hipLaunchKernelGGL(k1_support, dim3(512), dim3(256), 0, stream, x, W1f, Stf);
  hipLaunchKernelGGL(k2_hidden,  dim3(256), dim3(512), 0, stream, adj, Stf, b1, H);
  hipLaunchKernelGGL(k3_s2,      dim3(128), dim3(256), 0, stream, H, W2, S2f);
  hipLaunchKernelGGL(k4_out,     dim3(256), dim3(512), 0, stream, adj, S2f, b2, out);
}